// Round 18
// baseline (175.782 us; speedup 1.0000x reference)
//
#include <hip/hip_runtime.h>
#include <hip/hip_bf16.h>

#define SEQ 4096
#define NB 64
#define H2 256
#define MROWS (SEQ * NB)   // 262144

typedef short bf16x8 __attribute__((ext_vector_type(8)));
typedef int   i32x4  __attribute__((ext_vector_type(4)));
typedef float f32x4  __attribute__((ext_vector_type(4)));

__device__ __forceinline__ float fast_tanh(float x) {
    float e = __expf(2.0f * x);
    return 1.0f - 2.0f * __builtin_amdgcn_rcpf(e + 1.0f);
}

// -------- pack W (fp32 [256][256] d-major) -> bf16 MFMA B-fragment order ----
// Wp[((kk*16+n)*64 + l)*8 + i] = bf16(W[(kk*32 + 8*(l>>4) + i)*256 + n*16 + (l&15)])
__global__ __launch_bounds__(256)
void pack_w_kernel(const float* __restrict__ W, __hip_bfloat16* __restrict__ Wp) {
    int t = blockIdx.x * 256 + threadIdx.x;   // 0..8191
    int l  = t & 63;
    int n  = (t >> 6) & 15;
    int kk = t >> 10;
    int e  = n * 16 + (l & 15);
    int d0 = kk * 32 + 8 * (l >> 4);
    union { __hip_bfloat16 h[8]; i32x4 v; } cv;
#pragma unroll
    for (int i = 0; i < 8; ++i) cv.h[i] = __float2bfloat16(W[(d0 + i) * H2 + e]);
    *reinterpret_cast<i32x4*>(&Wp[(size_t)t * 8]) = cv.v;
}

// -------- LDS-free fused MFMA logits: enc -> attnS[s*64+b] ------------------
// 64 rows/block, 4 waves (16 rows each). A-frags straight from global enc
// (fp32->bf16 in-reg); B-frags straight from L2-resident Wp. No barriers.
__global__ __launch_bounds__(256, 4)
void mfma_logits_kernel(const float* __restrict__ enc,
                        const __hip_bfloat16* __restrict__ Wp,
                        const float* __restrict__ bias,
                        const float* __restrict__ proj,
                        float* __restrict__ attnS) {
    const int tid   = threadIdx.x;
    const int lane  = tid & 63;
    const int w     = tid >> 6;
    const int rloc  = lane & 15;       // A-row / D-col selector
    const int kslot = lane >> 4;       // k-slot (8 d's each)
    const long r0   = (long)blockIdx.x * 64;
    const long row  = r0 + w * 16 + rloc;

    const float* encRow = enc + (size_t)row * H2 + kslot * 8;
    const __hip_bfloat16* WpL = Wp + (size_t)lane * 8;

    f32x4 acc[16];
#pragma unroll
    for (int n = 0; n < 16; ++n) acc[n] = (f32x4)(0.0f);

#pragma unroll
    for (int kk = 0; kk < 8; ++kk) {
        float4 a0 = *reinterpret_cast<const float4*>(encRow + kk * 32);
        float4 a1 = *reinterpret_cast<const float4*>(encRow + kk * 32 + 4);
        union { __hip_bfloat16 h[8]; bf16x8 v; } af;
        af.h[0] = __float2bfloat16(a0.x); af.h[1] = __float2bfloat16(a0.y);
        af.h[2] = __float2bfloat16(a0.z); af.h[3] = __float2bfloat16(a0.w);
        af.h[4] = __float2bfloat16(a1.x); af.h[5] = __float2bfloat16(a1.y);
        af.h[6] = __float2bfloat16(a1.z); af.h[7] = __float2bfloat16(a1.w);
#pragma unroll
        for (int n = 0; n < 16; ++n) {
            bf16x8 bv = *reinterpret_cast<const bf16x8*>(WpL + (size_t)(kk * 16 + n) * 512);
            acc[n] = __builtin_amdgcn_mfma_f32_16x16x32_bf16(af.v, bv, acc[n], 0, 0, 0);
        }
    }

    // epilogue: logit = sum_e proj[e] * tanh(acc + bias[e])
    // D: col = n*16 + rloc, row = kslot*4 + r  (within the wave's 16-row tile)
    float biasv[16], projv[16];
#pragma unroll
    for (int n = 0; n < 16; ++n) {
        int e = n * 16 + rloc;
        biasv[n] = bias[e];
        projv[n] = proj[e];
    }
    float pv[4];
#pragma unroll
    for (int r = 0; r < 4; ++r) {
        float p = 0.0f;
#pragma unroll
        for (int n = 0; n < 16; ++n) {
            p += projv[n] * fast_tanh(acc[n][r] + biasv[n]);
        }
        p += __shfl_xor(p, 1);
        p += __shfl_xor(p, 2);
        p += __shfl_xor(p, 4);
        p += __shfl_xor(p, 8);
        pv[r] = p;
    }
    if (rloc == 0) {
        long orow = r0 + w * 16 + kslot * 4;
        float4 o; o.x = pv[0]; o.y = pv[1]; o.z = pv[2]; o.w = pv[3];
        *reinterpret_cast<float4*>(&attnS[orow]) = o;   // [s][b] flat rows
    }
}

// -------- softmax over s per batch; logits [s][b] -> attn out [b][s] --------
__global__ void r18_softmax(const float* __restrict__ attnS,
                            float* __restrict__ out_attn) {
    __shared__ float sL[SEQ];
    __shared__ float red[256];
    const int b = blockIdx.x;
    const int t = threadIdx.x;

    float lm = -1e30f;
    for (int s = t; s < SEQ; s += 256) {
        float v = attnS[(size_t)s * NB + b];
        sL[s] = v;
        lm = fmaxf(lm, v);
    }
    red[t] = lm;
    __syncthreads();
    for (int h = 128; h > 0; h >>= 1) {
        if (t < h) red[t] = fmaxf(red[t], red[t + h]);
        __syncthreads();
    }
    const float gmax = red[0];
    __syncthreads();

    float ls = 0.0f;
    for (int s = t; s < SEQ; s += 256) {
        float e = __expf(sL[s] - gmax);
        sL[s] = e;
        ls += e;
    }
    red[t] = ls;
    __syncthreads();
    for (int h = 128; h > 0; h >>= 1) {
        if (t < h) red[t] += red[t + h];
        __syncthreads();
    }
    const float inv = 1.0f / red[0];

    for (int s = t; s < SEQ; s += 256) {
        out_attn[(size_t)b * SEQ + s] = sL[s] * inv;
    }
}

// -------- float4 weighted sums over s-chunks of 256, enc [s][b][d] ----------
__global__ __launch_bounds__(256)
void r18_wsum(const float* __restrict__ enc,
              const float* __restrict__ out_attn,
              float* __restrict__ partials) {
    __shared__ float wl[256];
    __shared__ float4 pf[4][64];
    const int b  = blockIdx.x & 63;
    const int c  = blockIdx.x >> 6;      // 0..15
    const int t  = threadIdx.x;
    const int dq = t & 63;               // float4 group over d
    const int sq = t >> 6;               // s-subgroup 0..3

    wl[t] = out_attn[(size_t)b * SEQ + c * 256 + t];
    __syncthreads();

    float4 acc = make_float4(0.f, 0.f, 0.f, 0.f);
    const size_t base = ((size_t)(c * 256 + sq * 64) * NB + b) * H2 + dq * 4;
#pragma unroll 4
    for (int j = 0; j < 64; ++j) {
        float wv = wl[sq * 64 + j];
        float4 ev = *reinterpret_cast<const float4*>(&enc[base + (size_t)j * NB * H2]);
        acc.x = fmaf(wv, ev.x, acc.x);
        acc.y = fmaf(wv, ev.y, acc.y);
        acc.z = fmaf(wv, ev.z, acc.z);
        acc.w = fmaf(wv, ev.w, acc.w);
    }
    pf[sq][dq] = acc;
    __syncthreads();
    if (sq == 0) {
        float4 a = pf[0][dq], b1 = pf[1][dq], c1 = pf[2][dq], d1 = pf[3][dq];
        float4 o;
        o.x = a.x + b1.x + c1.x + d1.x;
        o.y = a.y + b1.y + c1.y + d1.y;
        o.z = a.z + b1.z + c1.z + d1.z;
        o.w = a.w + b1.w + c1.w + d1.w;
        *reinterpret_cast<float4*>(&partials[((size_t)c * NB + b) * H2 + dq * 4]) = o;
    }
}

// -------- final reduce over the 16 chunks; fp32 vectors out -----------------
__global__ void r18_reduce(const float* __restrict__ partials,
                           float* __restrict__ out_vec) {
    const int b = blockIdx.x;
    const int t = threadIdx.x;           // = d
    float a = 0.0f;
    for (int c = 0; c < 16; ++c)
        a += partials[((size_t)c * NB + b) * H2 + t];
    out_vec[(size_t)b * H2 + t] = a;
}

extern "C" void kernel_launch(void* const* d_in, const int* in_sizes, int n_in,
                              void* d_out, int out_size, void* d_ws, size_t ws_size,
                              hipStream_t stream) {
    const float* enc  = (const float*)d_in[0];
    const float* W    = (const float*)d_in[1];
    const float* bias = (const float*)d_in[2];
    const float* proj = (const float*)d_in[3];

    float* out      = (float*)d_out;                 // FLOAT32 outputs
    float* out_vec  = out;                           // [1][64][256]
    float* out_attn = out + NB * H2;                 // [64][4096]

    char* ws = (char*)d_ws;
    __hip_bfloat16* Wp = (__hip_bfloat16*)ws;        // 128 KiB packed W
    float* attnS    = (float*)(ws + 131072);         // 1 MiB fp32 logits [s][b]
    float* partials = (float*)(ws + 131072 + (1u << 20));  // 1 MiB

    hipLaunchKernelGGL(pack_w_kernel,      dim3(32),         dim3(256), 0, stream,
                       W, Wp);
    hipLaunchKernelGGL(mfma_logits_kernel, dim3(MROWS / 64), dim3(256), 0, stream,
                       enc, Wp, bias, proj, attnS);
    hipLaunchKernelGGL(r18_softmax,        dim3(NB),         dim3(256), 0, stream,
                       attnS, out_attn);
    hipLaunchKernelGGL(r18_wsum,           dim3(16 * NB),    dim3(256), 0, stream,
                       enc, out_attn, partials);
    hipLaunchKernelGGL(r18_reduce,         dim3(NB),         dim3(256), 0, stream,
                       partials, out_vec);
}

// Round 19
// 159.305 us; speedup vs baseline: 1.1034x; 1.1034x over previous
//
#include <hip/hip_runtime.h>
#include <hip/hip_bf16.h>

#define SEQ 4096
#define NB 64
#define H2 256
#define MROWS (SEQ * NB)   // 262144

typedef short bf16x8 __attribute__((ext_vector_type(8)));
typedef int   i32x4  __attribute__((ext_vector_type(4)));
typedef float f32x4  __attribute__((ext_vector_type(4)));

__device__ __forceinline__ float fast_tanh(float x) {
    float e = __expf(2.0f * x);
    return 1.0f - 2.0f * __builtin_amdgcn_rcpf(e + 1.0f);
}

// -------- pack W (fp32 [256][256] d-major) -> bf16 MFMA B-fragment order ----
// Wp[((kk*16+n)*64 + l)*8 + i] = bf16(W[(kk*32 + 8*(l>>4) + i)*256 + n*16 + (l&15)])
__global__ __launch_bounds__(256)
void pack_w_kernel(const float* __restrict__ W, __hip_bfloat16* __restrict__ Wp) {
    int t = blockIdx.x * 256 + threadIdx.x;   // 0..8191
    int l  = t & 63;
    int n  = (t >> 6) & 15;
    int kk = t >> 10;
    int e  = n * 16 + (l & 15);
    int d0 = kk * 32 + 8 * (l >> 4);
    union { __hip_bfloat16 h[8]; i32x4 v; } cv;
#pragma unroll
    for (int i = 0; i < 8; ++i) cv.h[i] = __float2bfloat16(W[(d0 + i) * H2 + e]);
    *reinterpret_cast<i32x4*>(&Wp[(size_t)t * 8]) = cv.v;
}

// -------- logits GEMM: 64 rows x 128 cols per block, BK=64, dbuf LDS --------
// Block (rowblk, cb): partial_cb[row] = sum_{e in cb's 128} proj[e]*tanh(z+bias)
// logit[row] = partial_0[row] + partial_1[row]  (tanh elementwise in e)
__global__ __launch_bounds__(256)
void logits_gemm_kernel(const float* __restrict__ enc,
                        const __hip_bfloat16* __restrict__ Wp,
                        const float* __restrict__ bias,
                        const float* __restrict__ proj,
                        float* __restrict__ attnP) {
    __shared__ __hip_bfloat16 aT[2][64][72];   // 64 rows x 64 d (pad->72) = 18KB
    __shared__ __hip_bfloat16 wT[2][8192];     // 2 kk32 x 8 frags x 512 = 32KB

    const int tid   = threadIdx.x;
    const int lane  = tid & 63;
    const int w     = tid >> 6;          // wave 0..3 -> rows w*16..+15
    const int rloc  = lane & 15;
    const int kslot = lane >> 4;
    const int rowblk = blockIdx.x >> 1;
    const int cb     = blockIdx.x & 1;   // col half: e in [cb*128, cb*128+128)
    const long r0    = (long)rowblk * 64;

    // A-staging decomposition: thread -> (row, 16-d segment)
    const int arow = tid >> 2;           // 0..63
    const int aseg = (tid & 3) * 16;     // 0,16,32,48 within BK=64

    f32x4 acc[8];
#pragma unroll
    for (int n = 0; n < 8; ++n) acc[n] = (f32x4)(0.0f);

    // ---------------- prologue: stage kt=0 into buf 0 ----------------
    {
        // A: rows r0.., d 0..63
        float4 a0 = *reinterpret_cast<const float4*>(&enc[(r0 + arow) * H2 + aseg]);
        float4 a1 = *reinterpret_cast<const float4*>(&enc[(r0 + arow) * H2 + aseg + 4]);
        float4 a2 = *reinterpret_cast<const float4*>(&enc[(r0 + arow) * H2 + aseg + 8]);
        float4 a3 = *reinterpret_cast<const float4*>(&enc[(r0 + arow) * H2 + aseg + 12]);
        union { __hip_bfloat16 h[16]; uint4 u[2]; } cv;
        cv.h[0] = __float2bfloat16(a0.x); cv.h[1] = __float2bfloat16(a0.y);
        cv.h[2] = __float2bfloat16(a0.z); cv.h[3] = __float2bfloat16(a0.w);
        cv.h[4] = __float2bfloat16(a1.x); cv.h[5] = __float2bfloat16(a1.y);
        cv.h[6] = __float2bfloat16(a1.z); cv.h[7] = __float2bfloat16(a1.w);
        cv.h[8] = __float2bfloat16(a2.x); cv.h[9] = __float2bfloat16(a2.y);
        cv.h[10] = __float2bfloat16(a2.z); cv.h[11] = __float2bfloat16(a2.w);
        cv.h[12] = __float2bfloat16(a3.x); cv.h[13] = __float2bfloat16(a3.y);
        cv.h[14] = __float2bfloat16(a3.z); cv.h[15] = __float2bfloat16(a3.w);
        *reinterpret_cast<uint4*>(&aT[0][arow][aseg])     = cv.u[0];
        *reinterpret_cast<uint4*>(&aT[0][arow][aseg + 8]) = cv.u[1];
        // W: kk32 pair {0,1}, our cb's 8 frags each (4096 elems per kk32)
#pragma unroll
        for (int j = 0; j < 4; ++j) {
            int L = j * 2048 + tid * 8;
            const __hip_bfloat16* src = (j < 2)
                ? &Wp[(size_t)((0 * 16 + cb * 8) * 512) + L]
                : &Wp[(size_t)((1 * 16 + cb * 8) * 512) + (L - 4096)];
            i32x4 v = *reinterpret_cast<const i32x4*>(src);
            *reinterpret_cast<i32x4*>(&wT[0][L]) = v;
        }
    }
    __syncthreads();

    int buf = 0;
#pragma unroll
    for (int kt = 0; kt < 4; ++kt) {
        // prefetch next K-step into registers
        float4 a0, a1, a2, a3; i32x4 wv[4];
        if (kt < 3) {
            const float* ap = &enc[(r0 + arow) * H2 + (kt + 1) * 64 + aseg];
            a0 = *reinterpret_cast<const float4*>(ap);
            a1 = *reinterpret_cast<const float4*>(ap + 4);
            a2 = *reinterpret_cast<const float4*>(ap + 8);
            a3 = *reinterpret_cast<const float4*>(ap + 12);
#pragma unroll
            for (int j = 0; j < 4; ++j) {
                int L = j * 2048 + tid * 8;
                const __hip_bfloat16* src = (j < 2)
                    ? &Wp[(size_t)(((2 * (kt + 1)) * 16 + cb * 8) * 512) + L]
                    : &Wp[(size_t)(((2 * (kt + 1) + 1) * 16 + cb * 8) * 512) + (L - 4096)];
                wv[j] = *reinterpret_cast<const i32x4*>(src);
            }
        }
        // compute on current buffer: 2 kk32 sub-steps x 8 n-frags
#pragma unroll
        for (int kc = 0; kc < 2; ++kc) {
            bf16x8 af = *reinterpret_cast<const bf16x8*>(
                &aT[buf][w * 16 + rloc][kc * 32 + kslot * 8]);
#pragma unroll
            for (int n = 0; n < 8; ++n) {
                bf16x8 bv = *reinterpret_cast<const bf16x8*>(
                    &wT[buf][kc * 4096 + n * 512 + lane * 8]);
                acc[n] = __builtin_amdgcn_mfma_f32_16x16x32_bf16(af, bv, acc[n], 0, 0, 0);
            }
        }
        // write prefetched data into the other buffer
        if (kt < 3) {
            union { __hip_bfloat16 h[16]; uint4 u[2]; } cv;
            cv.h[0] = __float2bfloat16(a0.x); cv.h[1] = __float2bfloat16(a0.y);
            cv.h[2] = __float2bfloat16(a0.z); cv.h[3] = __float2bfloat16(a0.w);
            cv.h[4] = __float2bfloat16(a1.x); cv.h[5] = __float2bfloat16(a1.y);
            cv.h[6] = __float2bfloat16(a1.z); cv.h[7] = __float2bfloat16(a1.w);
            cv.h[8] = __float2bfloat16(a2.x); cv.h[9] = __float2bfloat16(a2.y);
            cv.h[10] = __float2bfloat16(a2.z); cv.h[11] = __float2bfloat16(a2.w);
            cv.h[12] = __float2bfloat16(a3.x); cv.h[13] = __float2bfloat16(a3.y);
            cv.h[14] = __float2bfloat16(a3.z); cv.h[15] = __float2bfloat16(a3.w);
            *reinterpret_cast<uint4*>(&aT[buf ^ 1][arow][aseg])     = cv.u[0];
            *reinterpret_cast<uint4*>(&aT[buf ^ 1][arow][aseg + 8]) = cv.u[1];
#pragma unroll
            for (int j = 0; j < 4; ++j) {
                int L = j * 2048 + tid * 8;
                *reinterpret_cast<i32x4*>(&wT[buf ^ 1][L]) = wv[j];
            }
        }
        __syncthreads();
        buf ^= 1;
    }

    // ---- epilogue: partial proj-dot of tanh over this block's 128 cols ----
    // D: col = n*16 + rloc (within cb), row = w*16 + kslot*4 + r
    float biasv[8], projv[8];
#pragma unroll
    for (int n = 0; n < 8; ++n) {
        int e = cb * 128 + n * 16 + rloc;
        biasv[n] = bias[e];
        projv[n] = proj[e];
    }
    float pv[4];
#pragma unroll
    for (int r = 0; r < 4; ++r) {
        float p = 0.0f;
#pragma unroll
        for (int n = 0; n < 8; ++n) {
            p += projv[n] * fast_tanh(acc[n][r] + biasv[n]);
        }
        p += __shfl_xor(p, 1);
        p += __shfl_xor(p, 2);
        p += __shfl_xor(p, 4);
        p += __shfl_xor(p, 8);
        pv[r] = p;
    }
    if (rloc == 0) {
        long orow = r0 + w * 16 + kslot * 4;
        float4 o; o.x = pv[0]; o.y = pv[1]; o.z = pv[2]; o.w = pv[3];
        *reinterpret_cast<float4*>(&attnP[(size_t)cb * MROWS + orow]) = o;
    }
}

// -------- softmax over s per batch; logit = partial0 + partial1 -------------
__global__ void r19_softmax(const float* __restrict__ attnP,
                            float* __restrict__ out_attn) {
    __shared__ float sL[SEQ];
    __shared__ float red[256];
    const int b = blockIdx.x;
    const int t = threadIdx.x;

    float lm = -1e30f;
    for (int s = t; s < SEQ; s += 256) {
        float v = attnP[(size_t)s * NB + b] + attnP[(size_t)MROWS + (size_t)s * NB + b];
        sL[s] = v;
        lm = fmaxf(lm, v);
    }
    red[t] = lm;
    __syncthreads();
    for (int h = 128; h > 0; h >>= 1) {
        if (t < h) red[t] = fmaxf(red[t], red[t + h]);
        __syncthreads();
    }
    const float gmax = red[0];
    __syncthreads();

    float ls = 0.0f;
    for (int s = t; s < SEQ; s += 256) {
        float e = __expf(sL[s] - gmax);
        sL[s] = e;
        ls += e;
    }
    red[t] = ls;
    __syncthreads();
    for (int h = 128; h > 0; h >>= 1) {
        if (t < h) red[t] += red[t + h];
        __syncthreads();
    }
    const float inv = 1.0f / red[0];

    for (int s = t; s < SEQ; s += 256) {
        out_attn[(size_t)b * SEQ + s] = sL[s] * inv;
    }
}

// -------- float4 weighted sums over s-chunks of 256, enc [s][b][d] ----------
__global__ __launch_bounds__(256)
void r19_wsum(const float* __restrict__ enc,
              const float* __restrict__ out_attn,
              float* __restrict__ partials) {
    __shared__ float wl[256];
    __shared__ float4 pf[4][64];
    const int b  = blockIdx.x & 63;
    const int c  = blockIdx.x >> 6;      // 0..15
    const int t  = threadIdx.x;
    const int dq = t & 63;               // float4 group over d
    const int sq = t >> 6;               // s-subgroup 0..3

    wl[t] = out_attn[(size_t)b * SEQ + c * 256 + t];
    __syncthreads();

    float4 acc = make_float4(0.f, 0.f, 0.f, 0.f);
    const size_t base = ((size_t)(c * 256 + sq * 64) * NB + b) * H2 + dq * 4;
#pragma unroll 4
    for (int j = 0; j < 64; ++j) {
        float wv = wl[sq * 64 + j];
        float4 ev = *reinterpret_cast<const float4*>(&enc[base + (size_t)j * NB * H2]);
        acc.x = fmaf(wv, ev.x, acc.x);
        acc.y = fmaf(wv, ev.y, acc.y);
        acc.z = fmaf(wv, ev.z, acc.z);
        acc.w = fmaf(wv, ev.w, acc.w);
    }
    pf[sq][dq] = acc;
    __syncthreads();
    if (sq == 0) {
        float4 a = pf[0][dq], b1 = pf[1][dq], c1 = pf[2][dq], d1 = pf[3][dq];
        float4 o;
        o.x = a.x + b1.x + c1.x + d1.x;
        o.y = a.y + b1.y + c1.y + d1.y;
        o.z = a.z + b1.z + c1.z + d1.z;
        o.w = a.w + b1.w + c1.w + d1.w;
        *reinterpret_cast<float4*>(&partials[((size_t)c * NB + b) * H2 + dq * 4]) = o;
    }
}

// -------- final reduce over the 16 chunks; fp32 vectors out -----------------
__global__ void r19_reduce(const float* __restrict__ partials,
                           float* __restrict__ out_vec) {
    const int b = blockIdx.x;
    const int t = threadIdx.x;           // = d
    float a = 0.0f;
    for (int c = 0; c < 16; ++c)
        a += partials[((size_t)c * NB + b) * H2 + t];
    out_vec[(size_t)b * H2 + t] = a;
}

extern "C" void kernel_launch(void* const* d_in, const int* in_sizes, int n_in,
                              void* d_out, int out_size, void* d_ws, size_t ws_size,
                              hipStream_t stream) {
    const float* enc  = (const float*)d_in[0];
    const float* W    = (const float*)d_in[1];
    const float* bias = (const float*)d_in[2];
    const float* proj = (const float*)d_in[3];

    float* out      = (float*)d_out;                 // FLOAT32 outputs
    float* out_vec  = out;                           // [1][64][256]
    float* out_attn = out + NB * H2;                 // [64][4096]

    char* ws = (char*)d_ws;
    __hip_bfloat16* Wp = (__hip_bfloat16*)ws;        // 128 KiB packed W
    float* attnP    = (float*)(ws + 131072);         // 2 MiB partial dots [2][s*64+b]
    float* partials = (float*)(ws + 131072 + (2u << 20));  // 1 MiB wsum partials

    hipLaunchKernelGGL(pack_w_kernel,      dim3(32),            dim3(256), 0, stream,
                       W, Wp);
    hipLaunchKernelGGL(logits_gemm_kernel, dim3(MROWS / 64 * 2), dim3(256), 0, stream,
                       enc, Wp, bias, proj, attnP);
    hipLaunchKernelGGL(r19_softmax,        dim3(NB),            dim3(256), 0, stream,
                       attnP, out_attn);
    hipLaunchKernelGGL(r19_wsum,           dim3(16 * NB),       dim3(256), 0, stream,
                       enc, out_attn, partials);
    hipLaunchKernelGGL(r19_reduce,         dim3(NB),            dim3(256), 0, stream,
                       partials, out_vec);
}

// Round 20
// 155.556 us; speedup vs baseline: 1.1300x; 1.0241x over previous
//
#include <hip/hip_runtime.h>
#include <hip/hip_bf16.h>

#define SEQ 4096
#define NB 64
#define H2 256
#define MROWS (SEQ * NB)   // 262144

typedef short bf16x8 __attribute__((ext_vector_type(8)));
typedef int   i32x4  __attribute__((ext_vector_type(4)));
typedef float f32x4  __attribute__((ext_vector_type(4)));

__device__ __forceinline__ float fast_tanh(float x) {
    float e = __expf(2.0f * x);
    return 1.0f - 2.0f * __builtin_amdgcn_rcpf(e + 1.0f);
}

// -------- pack W (fp32 [256][256] d-major) -> bf16 MFMA B-fragment order ----
// Wp[((kk*16+n)*64 + l)*8 + i] = bf16(W[(kk*32 + 8*(l>>4) + i)*256 + n*16 + (l&15)])
__global__ __launch_bounds__(256)
void pack_w_kernel(const float* __restrict__ W, __hip_bfloat16* __restrict__ Wp) {
    int t = blockIdx.x * 256 + threadIdx.x;   // 0..8191
    int l  = t & 63;
    int n  = (t >> 6) & 15;
    int kk = t >> 10;
    int e  = n * 16 + (l & 15);
    int d0 = kk * 32 + 8 * (l >> 4);
    union { __hip_bfloat16 h[8]; i32x4 v; } cv;
#pragma unroll
    for (int i = 0; i < 8; ++i) cv.h[i] = __float2bfloat16(W[(d0 + i) * H2 + e]);
    *reinterpret_cast<i32x4*>(&Wp[(size_t)t * 8]) = cv.v;
}

// -------- fused MFMA logits: A direct-global, W LDS dbuf, 1 barrier/kk ------
// 128 rows/block (4 waves x 2 row-tiles), full 256 cols, BK=32.
__global__ __launch_bounds__(256, 2)
void logits_kernel(const float* __restrict__ enc,
                   const __hip_bfloat16* __restrict__ Wp,
                   const float* __restrict__ bias,
                   const float* __restrict__ proj,
                   float* __restrict__ attnS) {
    __shared__ __hip_bfloat16 wT[2][8192];     // 16 KiB per buffer

    const int tid   = threadIdx.x;
    const int lane  = tid & 63;
    const int w     = tid >> 6;
    const int rloc  = lane & 15;
    const int kslot = lane >> 4;
    const long r0   = (long)blockIdx.x * 128;
    const long rowA = r0 + w * 32 + rloc;      // rt adds +16

    f32x4 acc[2][16];
#pragma unroll
    for (int rt = 0; rt < 2; ++rt)
#pragma unroll
        for (int n = 0; n < 16; ++n) acc[rt][n] = (f32x4)(0.0f);

    // stage W chunk 0 (16 KiB linear copy)
#pragma unroll
    for (int j = 0; j < 4; ++j) {
        i32x4 v = *reinterpret_cast<const i32x4*>(Wp + j * 2048 + tid * 8);
        *reinterpret_cast<i32x4*>(&wT[0][j * 2048 + tid * 8]) = v;
    }
    __syncthreads();

    int buf = 0;
#pragma unroll
    for (int kk = 0; kk < 8; ++kk) {
        // prefetch next W chunk into registers (L2-resident)
        i32x4 wv[4];
        if (kk < 7) {
#pragma unroll
            for (int j = 0; j < 4; ++j)
                wv[j] = *reinterpret_cast<const i32x4*>(
                    Wp + (size_t)(kk + 1) * 8192 + j * 2048 + tid * 8);
        }
        // A fragments straight from global (64B-chunk coalesced, read once)
        bf16x8 af[2];
#pragma unroll
        for (int rt = 0; rt < 2; ++rt) {
            const float* ap = enc + (size_t)(rowA + rt * 16) * H2 + kk * 32 + kslot * 8;
            float4 a0 = *reinterpret_cast<const float4*>(ap);
            float4 a1 = *reinterpret_cast<const float4*>(ap + 4);
            union { __hip_bfloat16 h[8]; bf16x8 v; } cv;
            cv.h[0] = __float2bfloat16(a0.x); cv.h[1] = __float2bfloat16(a0.y);
            cv.h[2] = __float2bfloat16(a0.z); cv.h[3] = __float2bfloat16(a0.w);
            cv.h[4] = __float2bfloat16(a1.x); cv.h[5] = __float2bfloat16(a1.y);
            cv.h[6] = __float2bfloat16(a1.z); cv.h[7] = __float2bfloat16(a1.w);
            af[rt] = cv.v;
        }
        // MFMA over 16 column-fragments
#pragma unroll
        for (int n = 0; n < 16; ++n) {
            bf16x8 bv = *reinterpret_cast<const bf16x8*>(&wT[buf][n * 512 + lane * 8]);
            acc[0][n] = __builtin_amdgcn_mfma_f32_16x16x32_bf16(af[0], bv, acc[0][n], 0, 0, 0);
            acc[1][n] = __builtin_amdgcn_mfma_f32_16x16x32_bf16(af[1], bv, acc[1][n], 0, 0, 0);
        }
        // write prefetched W into the other buffer; single barrier per kk
        if (kk < 7) {
#pragma unroll
            for (int j = 0; j < 4; ++j)
                *reinterpret_cast<i32x4*>(&wT[buf ^ 1][j * 2048 + tid * 8]) = wv[j];
        }
        __syncthreads();
        buf ^= 1;
    }

    // ---- epilogue: logit = sum_e proj[e] * tanh(acc + bias[e]) ----
    // D: col = n*16 + rloc, row = r0 + w*32 + rt*16 + kslot*4 + r
    float biasv[16], projv[16];
#pragma unroll
    for (int n = 0; n < 16; ++n) {
        int e = n * 16 + rloc;
        biasv[n] = bias[e];
        projv[n] = proj[e];
    }
#pragma unroll
    for (int rt = 0; rt < 2; ++rt) {
        float pv[4];
#pragma unroll
        for (int r = 0; r < 4; ++r) {
            float p = 0.0f;
#pragma unroll
            for (int n = 0; n < 16; ++n) {
                p += projv[n] * fast_tanh(acc[rt][n][r] + biasv[n]);
            }
            p += __shfl_xor(p, 1);
            p += __shfl_xor(p, 2);
            p += __shfl_xor(p, 4);
            p += __shfl_xor(p, 8);
            pv[r] = p;
        }
        if (rloc == 0) {
            long orow = r0 + w * 32 + rt * 16 + kslot * 4;
            float4 o; o.x = pv[0]; o.y = pv[1]; o.z = pv[2]; o.w = pv[3];
            *reinterpret_cast<float4*>(&attnS[orow]) = o;   // [s][b] flat rows
        }
    }
}

// -------- softmax over s per batch; logits [s][b] -> attn out [b][s] --------
__global__ void r20_softmax(const float* __restrict__ attnS,
                            float* __restrict__ out_attn) {
    __shared__ float sL[SEQ];
    __shared__ float red[256];
    const int b = blockIdx.x;
    const int t = threadIdx.x;

    float lm = -1e30f;
    for (int s = t; s < SEQ; s += 256) {
        float v = attnS[(size_t)s * NB + b];
        sL[s] = v;
        lm = fmaxf(lm, v);
    }
    red[t] = lm;
    __syncthreads();
    for (int h = 128; h > 0; h >>= 1) {
        if (t < h) red[t] = fmaxf(red[t], red[t + h]);
        __syncthreads();
    }
    const float gmax = red[0];
    __syncthreads();

    float ls = 0.0f;
    for (int s = t; s < SEQ; s += 256) {
        float e = __expf(sL[s] - gmax);
        sL[s] = e;
        ls += e;
    }
    red[t] = ls;
    __syncthreads();
    for (int h = 128; h > 0; h >>= 1) {
        if (t < h) red[t] += red[t + h];
        __syncthreads();
    }
    const float inv = 1.0f / red[0];

    for (int s = t; s < SEQ; s += 256) {
        out_attn[(size_t)b * SEQ + s] = sL[s] * inv;
    }
}

// -------- float4 weighted sums over s-chunks of 256, enc [s][b][d] ----------
__global__ __launch_bounds__(256)
void r20_wsum(const float* __restrict__ enc,
              const float* __restrict__ out_attn,
              float* __restrict__ partials) {
    __shared__ float wl[256];
    __shared__ float4 pf[4][64];
    const int b  = blockIdx.x & 63;
    const int c  = blockIdx.x >> 6;      // 0..15
    const int t  = threadIdx.x;
    const int dq = t & 63;               // float4 group over d
    const int sq = t >> 6;               // s-subgroup 0..3

    wl[t] = out_attn[(size_t)b * SEQ + c * 256 + t];
    __syncthreads();

    float4 acc = make_float4(0.f, 0.f, 0.f, 0.f);
    const size_t base = ((size_t)(c * 256 + sq * 64) * NB + b) * H2 + dq * 4;
#pragma unroll 4
    for (int j = 0; j < 64; ++j) {
        float wv = wl[sq * 64 + j];
        float4 ev = *reinterpret_cast<const float4*>(&enc[base + (size_t)j * NB * H2]);
        acc.x = fmaf(wv, ev.x, acc.x);
        acc.y = fmaf(wv, ev.y, acc.y);
        acc.z = fmaf(wv, ev.z, acc.z);
        acc.w = fmaf(wv, ev.w, acc.w);
    }
    pf[sq][dq] = acc;
    __syncthreads();
    if (sq == 0) {
        float4 a = pf[0][dq], b1 = pf[1][dq], c1 = pf[2][dq], d1 = pf[3][dq];
        float4 o;
        o.x = a.x + b1.x + c1.x + d1.x;
        o.y = a.y + b1.y + c1.y + d1.y;
        o.z = a.z + b1.z + c1.z + d1.z;
        o.w = a.w + b1.w + c1.w + d1.w;
        *reinterpret_cast<float4*>(&partials[((size_t)c * NB + b) * H2 + dq * 4]) = o;
    }
}

// -------- final reduce over the 16 chunks; fp32 vectors out -----------------
__global__ void r20_reduce(const float* __restrict__ partials,
                           float* __restrict__ out_vec) {
    const int b = blockIdx.x;
    const int t = threadIdx.x;           // = d
    float a = 0.0f;
    for (int c = 0; c < 16; ++c)
        a += partials[((size_t)c * NB + b) * H2 + t];
    out_vec[(size_t)b * H2 + t] = a;
}

extern "C" void kernel_launch(void* const* d_in, const int* in_sizes, int n_in,
                              void* d_out, int out_size, void* d_ws, size_t ws_size,
                              hipStream_t stream) {
    const float* enc  = (const float*)d_in[0];
    const float* W    = (const float*)d_in[1];
    const float* bias = (const float*)d_in[2];
    const float* proj = (const float*)d_in[3];

    float* out      = (float*)d_out;                 // FLOAT32 outputs
    float* out_vec  = out;                           // [1][64][256]
    float* out_attn = out + NB * H2;                 // [64][4096]

    char* ws = (char*)d_ws;
    __hip_bfloat16* Wp = (__hip_bfloat16*)ws;        // 128 KiB packed W
    float* attnS    = (float*)(ws + 131072);         // 1 MiB fp32 logits [s][b]
    float* partials = (float*)(ws + 131072 + (1u << 20));  // 1 MiB wsum partials

    hipLaunchKernelGGL(pack_w_kernel,  dim3(32),          dim3(256), 0, stream,
                       W, Wp);
    hipLaunchKernelGGL(logits_kernel,  dim3(MROWS / 128), dim3(256), 0, stream,
                       enc, Wp, bias, proj, attnS);
    hipLaunchKernelGGL(r20_softmax,    dim3(NB),          dim3(256), 0, stream,
                       attnS, out_attn);
    hipLaunchKernelGGL(r20_wsum,       dim3(16 * NB),     dim3(256), 0, stream,
                       enc, out_attn, partials);
    hipLaunchKernelGGL(r20_reduce,     dim3(NB),          dim3(256), 0, stream,
                       partials, out_vec);
}

// Round 21
// 153.523 us; speedup vs baseline: 1.1450x; 1.0132x over previous
//
#include <hip/hip_runtime.h>
#include <hip/hip_bf16.h>

#define SEQ 4096
#define NB 64
#define H2 256

typedef short bf16x8 __attribute__((ext_vector_type(8)));
typedef int   i32x4  __attribute__((ext_vector_type(4)));
typedef float f32x4  __attribute__((ext_vector_type(4)));

__device__ __forceinline__ float fast_tanh(float x) {
    float e = __expf(2.0f * x);
    return 1.0f - 2.0f * __builtin_amdgcn_rcpf(e + 1.0f);
}

// -------- pack W (fp32 [256][256] d-major) -> bf16 MFMA B-fragment order ----
__global__ __launch_bounds__(256)
void pack_w_kernel(const float* __restrict__ W, __hip_bfloat16* __restrict__ Wp) {
    int t = blockIdx.x * 256 + threadIdx.x;   // 0..8191
    int l  = t & 63;
    int n  = (t >> 6) & 15;
    int kk = t >> 10;
    int e  = n * 16 + (l & 15);
    int d0 = kk * 32 + 8 * (l >> 4);
    union { __hip_bfloat16 h[8]; i32x4 v; } cv;
#pragma unroll
    for (int i = 0; i < 8; ++i) cv.h[i] = __float2bfloat16(W[(d0 + i) * H2 + e]);
    *reinterpret_cast<i32x4*>(&Wp[(size_t)t * 8]) = cv.v;
}

// -------- fused: logits + unnormalized-softmax + weighted-sum, ONE enc pass -
// Block (b, c): batch b, s-chunk c (512 s). 8 sub-tiles of 64 s-rows.
// Outputs: logits[b][s] (fp32), l_p[c*64+b], vec_p[(c*64+b)*256+d].
__global__ __launch_bounds__(256, 2)
void fused_kernel(const float* __restrict__ enc,
                  const __hip_bfloat16* __restrict__ Wp,
                  const float* __restrict__ bias,
                  const float* __restrict__ proj,
                  float* __restrict__ logits,
                  float* __restrict__ vec_p,
                  float* __restrict__ l_p) {
    __shared__ __hip_bfloat16 aT[64][264];   // 33.8 KB, pad 256->264
    __shared__ __hip_bfloat16 wT[2][8192];   // 32 KB
    __shared__ float lbuf[64];               // exp(logit) per sub-tile row

    const int tid   = threadIdx.x;
    const int lane  = tid & 63;
    const int w     = tid >> 6;
    const int rloc  = lane & 15;
    const int kslot = lane >> 4;
    const int b     = blockIdx.x & 63;
    const int c     = blockIdx.x >> 6;       // 0..7

    // A-staging split: 4 threads per row, 64 d's each
    const int ar   = tid >> 2;               // 0..63
    const int dseg = (tid & 3) * 64;

    float biasv[16], projv[16];
#pragma unroll
    for (int n = 0; n < 16; ++n) {
        int e = n * 16 + rloc;
        biasv[n] = bias[e];
        projv[n] = proj[e];
    }

    float vacc = 0.0f;
    float lsum = 0.0f;

    for (int t = 0; t < 8; ++t) {
        const int s0 = c * 512 + t * 64;
        __syncthreads();   // previous accum phase done reading aT

        // ---- stage A: 64 rows x 256 d -> bf16 aT ----
        {
            const float* src = enc + ((size_t)(s0 + ar) * NB + b) * H2 + dseg;
            float4 v[16];
#pragma unroll
            for (int i = 0; i < 16; ++i)
                v[i] = *reinterpret_cast<const float4*>(src + i * 4);
#pragma unroll
            for (int j = 0; j < 8; ++j) {
                union { __hip_bfloat16 h[8]; uint4 u; } cv;
                float4 va = v[2 * j], vb = v[2 * j + 1];
                cv.h[0] = __float2bfloat16(va.x); cv.h[1] = __float2bfloat16(va.y);
                cv.h[2] = __float2bfloat16(va.z); cv.h[3] = __float2bfloat16(va.w);
                cv.h[4] = __float2bfloat16(vb.x); cv.h[5] = __float2bfloat16(vb.y);
                cv.h[6] = __float2bfloat16(vb.z); cv.h[7] = __float2bfloat16(vb.w);
                *reinterpret_cast<uint4*>(&aT[ar][dseg + 8 * j]) = cv.u;
            }
        }
        // ---- stage W chunk 0 ----
#pragma unroll
        for (int j = 0; j < 4; ++j) {
            i32x4 v = *reinterpret_cast<const i32x4*>(Wp + j * 2048 + tid * 8);
            *reinterpret_cast<i32x4*>(&wT[0][j * 2048 + tid * 8]) = v;
        }
        __syncthreads();

        // ---- K-loop: 8 x BK32, W double-buffered ----
        f32x4 acc[16];
#pragma unroll
        for (int n = 0; n < 16; ++n) acc[n] = (f32x4)(0.0f);

        int buf = 0;
#pragma unroll
        for (int kk = 0; kk < 8; ++kk) {
            i32x4 wv[4];
            if (kk < 7) {
#pragma unroll
                for (int j = 0; j < 4; ++j)
                    wv[j] = *reinterpret_cast<const i32x4*>(
                        Wp + (size_t)(kk + 1) * 8192 + j * 2048 + tid * 8);
            }
            bf16x8 af = *reinterpret_cast<const bf16x8*>(
                &aT[w * 16 + rloc][kk * 32 + kslot * 8]);
#pragma unroll
            for (int n = 0; n < 16; ++n) {
                bf16x8 bv = *reinterpret_cast<const bf16x8*>(&wT[buf][n * 512 + lane * 8]);
                acc[n] = __builtin_amdgcn_mfma_f32_16x16x32_bf16(af, bv, acc[n], 0, 0, 0);
            }
            if (kk < 7) {
#pragma unroll
                for (int j = 0; j < 4; ++j)
                    *reinterpret_cast<i32x4*>(&wT[buf ^ 1][j * 2048 + tid * 8]) = wv[j];
            }
            __syncthreads();
            buf ^= 1;
        }

        // ---- epilogue: logit + exp; rows w*16 + kslot*4 + r ----
        float pv[4];
#pragma unroll
        for (int r = 0; r < 4; ++r) {
            float p = 0.0f;
#pragma unroll
            for (int n = 0; n < 16; ++n)
                p += projv[n] * fast_tanh(acc[n][r] + biasv[n]);
            p += __shfl_xor(p, 1);
            p += __shfl_xor(p, 2);
            p += __shfl_xor(p, 4);
            p += __shfl_xor(p, 8);
            pv[r] = p;
        }
        if (rloc == 0) {
            int rbase = w * 16 + kslot * 4;
            float4 o; o.x = pv[0]; o.y = pv[1]; o.z = pv[2]; o.w = pv[3];
            *reinterpret_cast<float4*>(&logits[(size_t)b * SEQ + s0 + rbase]) = o;
            float4 e;
            e.x = __expf(pv[0]); e.y = __expf(pv[1]);
            e.z = __expf(pv[2]); e.w = __expf(pv[3]);
            *reinterpret_cast<float4*>(&lbuf[rbase]) = e;
        }
        __syncthreads();

        // ---- weighted accumulation from the still-resident aT tile ----
        // thread owns d = tid; lbuf reads are wave-broadcast
#pragma unroll 8
        for (int r = 0; r < 64; ++r) {
            float pe = lbuf[r];
            lsum += pe;
            vacc = fmaf(pe, __bfloat162float(aT[r][tid]), vacc);
        }
    }

    vec_p[((size_t)c * NB + b) * H2 + tid] = vacc;
    if (tid == 0) l_p[c * NB + b] = lsum;
}

// -------- combine: l, vectors, and p writeback ------------------------------
__global__ __launch_bounds__(256)
void combine_kernel(const float* __restrict__ logits,
                    const float* __restrict__ vec_p,
                    const float* __restrict__ l_p,
                    float* __restrict__ out_vec,
                    float* __restrict__ out_attn) {
    const int b = blockIdx.x;
    const int t = threadIdx.x;

    float l = 0.0f;
#pragma unroll
    for (int c = 0; c < 8; ++c) l += l_p[c * NB + b];

    float v = 0.0f;
#pragma unroll
    for (int c = 0; c < 8; ++c) v += vec_p[((size_t)c * NB + b) * H2 + t];
    const float invl = 1.0f / l;
    out_vec[(size_t)b * H2 + t] = v * invl;

    for (int s = t; s < SEQ; s += 256) {
        out_attn[(size_t)b * SEQ + s] = __expf(logits[(size_t)b * SEQ + s]) * invl;
    }
}

extern "C" void kernel_launch(void* const* d_in, const int* in_sizes, int n_in,
                              void* d_out, int out_size, void* d_ws, size_t ws_size,
                              hipStream_t stream) {
    const float* enc  = (const float*)d_in[0];
    const float* W    = (const float*)d_in[1];
    const float* bias = (const float*)d_in[2];
    const float* proj = (const float*)d_in[3];

    float* out      = (float*)d_out;                 // FLOAT32 outputs
    float* out_vec  = out;                           // [1][64][256]
    float* out_attn = out + NB * H2;                 // [64][4096]

    char* ws = (char*)d_ws;
    __hip_bfloat16* Wp = (__hip_bfloat16*)ws;        // 128 KiB packed W
    float* logits = (float*)(ws + 131072);           // 1 MiB fp32 [b][s]
    float* vec_p  = (float*)(ws + 131072 + (1u << 20));          // 512 KiB
    float* l_p    = (float*)(ws + 131072 + (1u << 20) + 524288); // 2 KiB

    hipLaunchKernelGGL(pack_w_kernel,  dim3(32),  dim3(256), 0, stream, W, Wp);
    hipLaunchKernelGGL(fused_kernel,   dim3(512), dim3(256), 0, stream,
                       enc, Wp, bias, proj, logits, vec_p, l_p);
    hipLaunchKernelGGL(combine_kernel, dim3(NB),  dim3(256), 0, stream,
                       logits, vec_p, l_p, out_vec, out_attn);
}

// Round 22
// 149.280 us; speedup vs baseline: 1.1775x; 1.0284x over previous
//
#include <hip/hip_runtime.h>
#include <hip/hip_bf16.h>

#define SEQ 4096
#define NB 64
#define H2 256
#define MROWS (SEQ * NB)   // 262144

typedef short bf16x8 __attribute__((ext_vector_type(8)));
typedef int   i32x4  __attribute__((ext_vector_type(4)));
typedef float f32x4  __attribute__((ext_vector_type(4)));

__device__ __forceinline__ float fast_tanh(float x) {
    float e = __expf(2.0f * x);
    return 1.0f - 2.0f * __builtin_amdgcn_rcpf(e + 1.0f);
}

// -------- pack W (fp32 [256][256] d-major) -> bf16 MFMA B-fragment order ----
// Wp[((kk*16+n)*64 + l)*8 + i] = bf16(W[(kk*32 + 8*(l>>4) + i)*256 + n*16 + (l&15)])
__global__ __launch_bounds__(256)
void pack_w_kernel(const float* __restrict__ W, __hip_bfloat16* __restrict__ Wp) {
    int t = blockIdx.x * 256 + threadIdx.x;   // 0..8191
    int l  = t & 63;
    int n  = (t >> 6) & 15;
    int kk = t >> 10;
    int e  = n * 16 + (l & 15);
    int d0 = kk * 32 + 8 * (l >> 4);
    union { __hip_bfloat16 h[8]; i32x4 v; } cv;
#pragma unroll
    for (int i = 0; i < 8; ++i) cv.h[i] = __float2bfloat16(W[(d0 + i) * H2 + e]);
    *reinterpret_cast<i32x4*>(&Wp[(size_t)t * 8]) = cv.v;
}

// -------- fused MFMA logits: 64 rows/block, A+W LDS dbuf, 1 barrier/kk ------
// Occupancy-first variant of the R17 champion: acc 64 VGPR, 42 KB LDS
// -> 3 blocks/CU, 12 waves/CU (vs 8).
__global__ __launch_bounds__(256, 3)
void logits_kernel(const float* __restrict__ enc,
                   const __hip_bfloat16* __restrict__ Wp,
                   const float* __restrict__ bias,
                   const float* __restrict__ proj,
                   float* __restrict__ attnS) {
    __shared__ __hip_bfloat16 aT[2][64][40];   // 64 rows x 32 d (pad->40) 10.2KB
    __shared__ __hip_bfloat16 wT[2][8192];     // 16 KiB per buffer

    const int tid   = threadIdx.x;
    const int lane  = tid & 63;
    const int w     = tid >> 6;
    const int rloc  = lane & 15;
    const int kslot = lane >> 4;
    const long r0   = (long)blockIdx.x * 64;

    // A staging map: q in [0,512): row = q>>3 (0..63), dc = (q&7)*4
    const int ar0 = tid >> 3;            // rows for it=0: q=tid
    const int ad0 = (tid & 7) * 4;
    const int ar1 = (tid + 256) >> 3;    // rows for it=1
    const int ad1 = ad0;

    f32x4 acc[16];
#pragma unroll
    for (int n = 0; n < 16; ++n) acc[n] = (f32x4)(0.0f);

    // ---- prologue: stage chunk 0 ----
    {
        float4 v0 = *reinterpret_cast<const float4*>(&enc[(r0 + ar0) * H2 + ad0]);
        float4 v1 = *reinterpret_cast<const float4*>(&enc[(r0 + ar1) * H2 + ad1]);
        union { __hip_bfloat16 h[4]; uint2 u; } c0, c1;
        c0.h[0] = __float2bfloat16(v0.x); c0.h[1] = __float2bfloat16(v0.y);
        c0.h[2] = __float2bfloat16(v0.z); c0.h[3] = __float2bfloat16(v0.w);
        c1.h[0] = __float2bfloat16(v1.x); c1.h[1] = __float2bfloat16(v1.y);
        c1.h[2] = __float2bfloat16(v1.z); c1.h[3] = __float2bfloat16(v1.w);
        *reinterpret_cast<uint2*>(&aT[0][ar0][ad0]) = c0.u;
        *reinterpret_cast<uint2*>(&aT[0][ar1][ad1]) = c1.u;
#pragma unroll
        for (int j = 0; j < 4; ++j) {
            i32x4 v = *reinterpret_cast<const i32x4*>(Wp + j * 2048 + tid * 8);
            *reinterpret_cast<i32x4*>(&wT[0][j * 2048 + tid * 8]) = v;
        }
    }
    __syncthreads();

    int buf = 0;
#pragma unroll
    for (int kk = 0; kk < 8; ++kk) {
        // prefetch next K-chunk into registers
        float4 v0, v1; i32x4 wv[4];
        if (kk < 7) {
            v0 = *reinterpret_cast<const float4*>(&enc[(r0 + ar0) * H2 + (kk + 1) * 32 + ad0]);
            v1 = *reinterpret_cast<const float4*>(&enc[(r0 + ar1) * H2 + (kk + 1) * 32 + ad1]);
#pragma unroll
            for (int j = 0; j < 4; ++j)
                wv[j] = *reinterpret_cast<const i32x4*>(
                    Wp + (size_t)(kk + 1) * 8192 + j * 2048 + tid * 8);
        }
        // compute on current buffer
        bf16x8 af = *reinterpret_cast<const bf16x8*>(&aT[buf][w * 16 + rloc][kslot * 8]);
#pragma unroll
        for (int n = 0; n < 16; ++n) {
            bf16x8 bv = *reinterpret_cast<const bf16x8*>(&wT[buf][n * 512 + lane * 8]);
            acc[n] = __builtin_amdgcn_mfma_f32_16x16x32_bf16(af, bv, acc[n], 0, 0, 0);
        }
        // write prefetched data into the other buffer
        if (kk < 7) {
            union { __hip_bfloat16 h[4]; uint2 u; } c0, c1;
            c0.h[0] = __float2bfloat16(v0.x); c0.h[1] = __float2bfloat16(v0.y);
            c0.h[2] = __float2bfloat16(v0.z); c0.h[3] = __float2bfloat16(v0.w);
            c1.h[0] = __float2bfloat16(v1.x); c1.h[1] = __float2bfloat16(v1.y);
            c1.h[2] = __float2bfloat16(v1.z); c1.h[3] = __float2bfloat16(v1.w);
            *reinterpret_cast<uint2*>(&aT[buf ^ 1][ar0][ad0]) = c0.u;
            *reinterpret_cast<uint2*>(&aT[buf ^ 1][ar1][ad1]) = c1.u;
#pragma unroll
            for (int j = 0; j < 4; ++j)
                *reinterpret_cast<i32x4*>(&wT[buf ^ 1][j * 2048 + tid * 8]) = wv[j];
        }
        __syncthreads();
        buf ^= 1;
    }

    // ---- epilogue: logit = sum_e proj[e] * tanh(acc + bias[e]) ----
    // D: col = n*16 + rloc, row = w*16 + kslot*4 + r
    float biasv[16], projv[16];
#pragma unroll
    for (int n = 0; n < 16; ++n) {
        int e = n * 16 + rloc;
        biasv[n] = bias[e];
        projv[n] = proj[e];
    }
    float pv[4];
#pragma unroll
    for (int r = 0; r < 4; ++r) {
        float p = 0.0f;
#pragma unroll
        for (int n = 0; n < 16; ++n)
            p += projv[n] * fast_tanh(acc[n][r] + biasv[n]);
        p += __shfl_xor(p, 1);
        p += __shfl_xor(p, 2);
        p += __shfl_xor(p, 4);
        p += __shfl_xor(p, 8);
        pv[r] = p;
    }
    if (rloc == 0) {
        long orow = r0 + w * 16 + kslot * 4;
        float4 o; o.x = pv[0]; o.y = pv[1]; o.z = pv[2]; o.w = pv[3];
        *reinterpret_cast<float4*>(&attnS[orow]) = o;   // flat (s,b) rows
    }
}

// -------- softmax over s per batch; logits [s][b] -> attn out [b][s] --------
__global__ void r22_softmax(const float* __restrict__ attnS,
                            float* __restrict__ out_attn) {
    __shared__ float sL[SEQ];
    __shared__ float red[256];
    const int b = blockIdx.x;
    const int t = threadIdx.x;

    float lm = -1e30f;
    for (int s = t; s < SEQ; s += 256) {
        float v = attnS[(size_t)s * NB + b];
        sL[s] = v;
        lm = fmaxf(lm, v);
    }
    red[t] = lm;
    __syncthreads();
    for (int h = 128; h > 0; h >>= 1) {
        if (t < h) red[t] = fmaxf(red[t], red[t + h]);
        __syncthreads();
    }
    const float gmax = red[0];
    __syncthreads();

    float ls = 0.0f;
    for (int s = t; s < SEQ; s += 256) {
        float e = __expf(sL[s] - gmax);
        sL[s] = e;
        ls += e;
    }
    red[t] = ls;
    __syncthreads();
    for (int h = 128; h > 0; h >>= 1) {
        if (t < h) red[t] += red[t + h];
        __syncthreads();
    }
    const float inv = 1.0f / red[0];

    for (int s = t; s < SEQ; s += 256) {
        out_attn[(size_t)b * SEQ + s] = sL[s] * inv;
    }
}

// -------- float4 weighted sums over s-chunks of 128, enc [s][b][d] ----------
__global__ __launch_bounds__(256)
void r22_wsum(const float* __restrict__ enc,
              const float* __restrict__ out_attn,
              float* __restrict__ partials) {
    __shared__ float wl[128];
    __shared__ float4 pf[4][64];
    const int b  = blockIdx.x & 63;
    const int c  = blockIdx.x >> 6;      // 0..31
    const int t  = threadIdx.x;
    const int dq = t & 63;               // float4 group over d
    const int sq = t >> 6;               // s-subgroup 0..3 (32 s each)

    if (t < 128) wl[t] = out_attn[(size_t)b * SEQ + c * 128 + t];
    __syncthreads();

    float4 acc = make_float4(0.f, 0.f, 0.f, 0.f);
    const size_t base = ((size_t)(c * 128 + sq * 32) * NB + b) * H2 + dq * 4;
#pragma unroll 4
    for (int j = 0; j < 32; ++j) {
        float wv = wl[sq * 32 + j];
        float4 ev = *reinterpret_cast<const float4*>(&enc[base + (size_t)j * NB * H2]);
        acc.x = fmaf(wv, ev.x, acc.x);
        acc.y = fmaf(wv, ev.y, acc.y);
        acc.z = fmaf(wv, ev.z, acc.z);
        acc.w = fmaf(wv, ev.w, acc.w);
    }
    pf[sq][dq] = acc;
    __syncthreads();
    if (sq == 0) {
        float4 a = pf[0][dq], b1 = pf[1][dq], c1 = pf[2][dq], d1 = pf[3][dq];
        float4 o;
        o.x = a.x + b1.x + c1.x + d1.x;
        o.y = a.y + b1.y + c1.y + d1.y;
        o.z = a.z + b1.z + c1.z + d1.z;
        o.w = a.w + b1.w + c1.w + d1.w;
        *reinterpret_cast<float4*>(&partials[((size_t)c * NB + b) * H2 + dq * 4]) = o;
    }
}

// -------- final reduce over the 32 chunks; fp32 vectors out -----------------
__global__ void r22_reduce(const float* __restrict__ partials,
                           float* __restrict__ out_vec) {
    const int b = blockIdx.x;
    const int t = threadIdx.x;           // = d
    float a = 0.0f;
#pragma unroll
    for (int c = 0; c < 32; ++c)
        a += partials[((size_t)c * NB + b) * H2 + t];
    out_vec[(size_t)b * H2 + t] = a;
}

extern "C" void kernel_launch(void* const* d_in, const int* in_sizes, int n_in,
                              void* d_out, int out_size, void* d_ws, size_t ws_size,
                              hipStream_t stream) {
    const float* enc  = (const float*)d_in[0];
    const float* W    = (const float*)d_in[1];
    const float* bias = (const float*)d_in[2];
    const float* proj = (const float*)d_in[3];

    float* out      = (float*)d_out;                 // FLOAT32 outputs
    float* out_vec  = out;                           // [1][64][256]
    float* out_attn = out + NB * H2;                 // [64][4096]

    char* ws = (char*)d_ws;
    __hip_bfloat16* Wp = (__hip_bfloat16*)ws;        // 128 KiB packed W
    float* attnS    = (float*)(ws + 131072);         // 1 MiB fp32 logits (s,b) flat
    float* partials = (float*)(ws + 131072 + (1u << 20));  // 2 MiB wsum partials

    hipLaunchKernelGGL(pack_w_kernel,  dim3(32),         dim3(256), 0, stream,
                       W, Wp);
    hipLaunchKernelGGL(logits_kernel,  dim3(MROWS / 64), dim3(256), 0, stream,
                       enc, Wp, bias, proj, attnS);
    hipLaunchKernelGGL(r22_softmax,    dim3(NB),         dim3(256), 0, stream,
                       attnS, out_attn);
    hipLaunchKernelGGL(r22_wsum,       dim3(32 * NB),    dim3(256), 0, stream,
                       enc, out_attn, partials);
    hipLaunchKernelGGL(r22_reduce,     dim3(NB),         dim3(256), 0, stream,
                       partials, out_vec);
}

// Round 23
// 131.216 us; speedup vs baseline: 1.3396x; 1.1377x over previous
//
#include <hip/hip_runtime.h>
#include <hip/hip_bf16.h>

#define SEQ 4096
#define NB 64
#define H2 256
#define MROWS (SEQ * NB)   // 262144

typedef short bf16x8 __attribute__((ext_vector_type(8)));
typedef int   i32x4  __attribute__((ext_vector_type(4)));
typedef float f32x4  __attribute__((ext_vector_type(4)));

__device__ __forceinline__ float fast_tanh(float x) {
    float e = __expf(2.0f * x);
    return 1.0f - 2.0f * __builtin_amdgcn_rcpf(e + 1.0f);
}

// -------- pack W (fp32 [256][256] d-major) -> bf16 MFMA B-fragment order ----
// Wp[((kk*16+n)*64 + l)*8 + i] = bf16(W[(kk*32 + 8*(l>>4) + i)*256 + n*16 + (l&15)])
__global__ __launch_bounds__(256)
void pack_w_kernel(const float* __restrict__ W, __hip_bfloat16* __restrict__ Wp) {
    int t = blockIdx.x * 256 + threadIdx.x;   // 0..8191
    int l  = t & 63;
    int n  = (t >> 6) & 15;
    int kk = t >> 10;
    int e  = n * 16 + (l & 15);
    int d0 = kk * 32 + 8 * (l >> 4);
    union { __hip_bfloat16 h[8]; i32x4 v; } cv;
#pragma unroll
    for (int i = 0; i < 8; ++i) cv.h[i] = __float2bfloat16(W[(d0 + i) * H2 + e]);
    *reinterpret_cast<i32x4*>(&Wp[(size_t)t * 8]) = cv.v;
}

// -------- fused MFMA GEMM + tanh + proj-dot -> fp32 logits attnS[s*64+b] ----
// R17 champion structure, unchanged: 128 rows/block, A+W LDS double-buffered.
__global__ __launch_bounds__(256, 2)
void mfma_logits_kernel(const float* __restrict__ enc,
                        const __hip_bfloat16* __restrict__ Wp,
                        const float* __restrict__ bias,
                        const float* __restrict__ proj,
                        float* __restrict__ attnS) {
    __shared__ __hip_bfloat16 aT[2][128][40];   // 128 rows x 32 d (pad->40)
    __shared__ __hip_bfloat16 wT[2][8192];      // 16 KiB W-chunk per K-step

    const int tid  = threadIdx.x;
    const int lane = tid & 63;
    const int w    = tid >> 6;
    const long r0  = (long)blockIdx.x * 128;

    f32x4 acc[2][16];
#pragma unroll
    for (int rt = 0; rt < 2; ++rt)
#pragma unroll
        for (int n = 0; n < 16; ++n) acc[rt][n] = (f32x4)(0.0f);

    // ---- prologue: stage K-chunk 0 ----
#pragma unroll
    for (int it = 0; it < 4; ++it) {
        int q = it * 256 + tid;
        int row = q >> 3;
        int dc = (q & 7) * 4;
        float4 v = *reinterpret_cast<const float4*>(&enc[(r0 + row) * H2 + dc]);
        union { __hip_bfloat16 h[4]; uint2 u; } cv;
        cv.h[0] = __float2bfloat16(v.x); cv.h[1] = __float2bfloat16(v.y);
        cv.h[2] = __float2bfloat16(v.z); cv.h[3] = __float2bfloat16(v.w);
        *reinterpret_cast<uint2*>(&aT[0][row][dc]) = cv.u;
        i32x4 wv = *reinterpret_cast<const i32x4*>(&Wp[q * 8]);
        *reinterpret_cast<i32x4*>(&wT[0][q * 8]) = wv;
    }
    __syncthreads();

    int buf = 0;
#pragma unroll
    for (int kk = 0; kk < 8; ++kk) {
        // prefetch next K-chunk into registers
        float4 av[4]; i32x4 wv[4];
        if (kk < 7) {
#pragma unroll
            for (int it = 0; it < 4; ++it) {
                int q = it * 256 + tid;
                int row = q >> 3;
                int dc = (q & 7) * 4;
                av[it] = *reinterpret_cast<const float4*>(
                    &enc[(r0 + row) * H2 + (kk + 1) * 32 + dc]);
                wv[it] = *reinterpret_cast<const i32x4*>(&Wp[(kk + 1) * 8192 + q * 8]);
            }
        }
        // compute on current buffer
        bf16x8 af[2];
#pragma unroll
        for (int rt = 0; rt < 2; ++rt)
            af[rt] = *reinterpret_cast<const bf16x8*>(
                &aT[buf][w * 32 + rt * 16 + (lane & 15)][8 * (lane >> 4)]);
#pragma unroll
        for (int n = 0; n < 16; ++n) {
            bf16x8 bv = *reinterpret_cast<const bf16x8*>(&wT[buf][(n * 64 + lane) * 8]);
            acc[0][n] = __builtin_amdgcn_mfma_f32_16x16x32_bf16(af[0], bv, acc[0][n], 0, 0, 0);
            acc[1][n] = __builtin_amdgcn_mfma_f32_16x16x32_bf16(af[1], bv, acc[1][n], 0, 0, 0);
        }
        // write next chunk to the other buffer
        if (kk < 7) {
#pragma unroll
            for (int it = 0; it < 4; ++it) {
                int q = it * 256 + tid;
                int row = q >> 3;
                int dc = (q & 7) * 4;
                union { __hip_bfloat16 h[4]; uint2 u; } cv;
                cv.h[0] = __float2bfloat16(av[it].x); cv.h[1] = __float2bfloat16(av[it].y);
                cv.h[2] = __float2bfloat16(av[it].z); cv.h[3] = __float2bfloat16(av[it].w);
                *reinterpret_cast<uint2*>(&aT[buf ^ 1][row][dc]) = cv.u;
                *reinterpret_cast<i32x4*>(&wT[buf ^ 1][q * 8]) = wv[it];
            }
        }
        __syncthreads();
        buf ^= 1;
    }

    // ---- epilogue: tanh + proj-dot + 16-lane reduce; fp32 store ----
    float biasv[16], projv[16];
#pragma unroll
    for (int n = 0; n < 16; ++n) {
        int e = n * 16 + (lane & 15);
        biasv[n] = bias[e];
        projv[n] = proj[e];
    }
#pragma unroll
    for (int rt = 0; rt < 2; ++rt) {
        float pv[4];
#pragma unroll
        for (int r = 0; r < 4; ++r) {
            float p = 0.0f;
#pragma unroll
            for (int n = 0; n < 16; ++n) {
                float z = acc[rt][n][r] + biasv[n];
                p += projv[n] * fast_tanh(z);
            }
            p += __shfl_xor(p, 1);
            p += __shfl_xor(p, 2);
            p += __shfl_xor(p, 4);
            p += __shfl_xor(p, 8);
            pv[r] = p;
        }
        if ((lane & 15) == 0) {
            long row = r0 + w * 32 + rt * 16 + (lane >> 4) * 4;
            float4 o; o.x = pv[0]; o.y = pv[1]; o.z = pv[2]; o.w = pv[3];
            *reinterpret_cast<float4*>(&attnS[row]) = o;   // [s][b] layout
        }
    }
}

// -------- softmax over s per batch; logits [s][b] -> attn out [b][s] --------
__global__ void r23_softmax(const float* __restrict__ attnS,
                            float* __restrict__ out_attn) {
    __shared__ float sL[SEQ];
    __shared__ float red[256];
    const int b = blockIdx.x;
    const int t = threadIdx.x;

    float lm = -1e30f;
    for (int s = t; s < SEQ; s += 256) {
        float v = attnS[(size_t)s * NB + b];
        sL[s] = v;
        lm = fmaxf(lm, v);
    }
    red[t] = lm;
    __syncthreads();
    for (int h = 128; h > 0; h >>= 1) {
        if (t < h) red[t] = fmaxf(red[t], red[t + h]);
        __syncthreads();
    }
    const float gmax = red[0];
    __syncthreads();

    float ls = 0.0f;
    for (int s = t; s < SEQ; s += 256) {
        float e = __expf(sL[s] - gmax);
        sL[s] = e;
        ls += e;
    }
    red[t] = ls;
    __syncthreads();
    for (int h = 128; h > 0; h >>= 1) {
        if (t < h) red[t] += red[t + h];
        __syncthreads();
    }
    const float inv = 1.0f / red[0];

    for (int s = t; s < SEQ; s += 256) {
        out_attn[(size_t)b * SEQ + s] = sL[s] * inv;
    }
}

// -------- float4 weighted sums over s-chunks of 256, enc [s][b][d] ----------
__global__ __launch_bounds__(256)
void r23_wsum(const float* __restrict__ enc,
              const float* __restrict__ out_attn,
              float* __restrict__ partials) {
    __shared__ float wl[256];
    __shared__ float4 pf[4][64];
    const int b  = blockIdx.x & 63;
    const int c  = blockIdx.x >> 6;      // 0..15
    const int t  = threadIdx.x;
    const int dq = t & 63;               // float4 group over d
    const int sq = t >> 6;               // s-subgroup 0..3 (64 s each)

    wl[t] = out_attn[(size_t)b * SEQ + c * 256 + t];
    __syncthreads();

    float4 acc = make_float4(0.f, 0.f, 0.f, 0.f);
    const size_t base = ((size_t)(c * 256 + sq * 64) * NB + b) * H2 + dq * 4;
#pragma unroll 4
    for (int j = 0; j < 64; ++j) {
        float wv = wl[sq * 64 + j];
        float4 ev = *reinterpret_cast<const float4*>(&enc[base + (size_t)j * NB * H2]);
        acc.x = fmaf(wv, ev.x, acc.x);
        acc.y = fmaf(wv, ev.y, acc.y);
        acc.z = fmaf(wv, ev.z, acc.z);
        acc.w = fmaf(wv, ev.w, acc.w);
    }
    pf[sq][dq] = acc;
    __syncthreads();
    if (sq == 0) {
        float4 a = pf[0][dq], b1 = pf[1][dq], c1 = pf[2][dq], d1 = pf[3][dq];
        float4 o;
        o.x = a.x + b1.x + c1.x + d1.x;
        o.y = a.y + b1.y + c1.y + d1.y;
        o.z = a.z + b1.z + c1.z + d1.z;
        o.w = a.w + b1.w + c1.w + d1.w;
        *reinterpret_cast<float4*>(&partials[((size_t)c * NB + b) * H2 + dq * 4]) = o;
    }
}

// -------- final reduce over the 16 chunks; fp32 vectors out -----------------
__global__ void r23_reduce(const float* __restrict__ partials,
                           float* __restrict__ out_vec) {
    const int b = blockIdx.x;
    const int t = threadIdx.x;           // = d
    float a = 0.0f;
#pragma unroll
    for (int c = 0; c < 16; ++c)
        a += partials[((size_t)c * NB + b) * H2 + t];
    out_vec[(size_t)b * H2 + t] = a;
}

extern "C" void kernel_launch(void* const* d_in, const int* in_sizes, int n_in,
                              void* d_out, int out_size, void* d_ws, size_t ws_size,
                              hipStream_t stream) {
    const float* enc  = (const float*)d_in[0];
    const float* W    = (const float*)d_in[1];
    const float* bias = (const float*)d_in[2];
    const float* proj = (const float*)d_in[3];

    float* out      = (float*)d_out;                 // FLOAT32 outputs
    float* out_vec  = out;                           // [1][64][256]
    float* out_attn = out + NB * H2;                 // [64][4096]

    char* ws = (char*)d_ws;
    __hip_bfloat16* Wp = (__hip_bfloat16*)ws;        // 128 KiB packed W
    float* attnS    = (float*)(ws + 131072);         // 1 MiB fp32 logits [s][b]
    float* partials = (float*)(ws + 131072 + (1u << 20));  // 1 MiB

    hipLaunchKernelGGL(pack_w_kernel,      dim3(32),          dim3(256), 0, stream,
                       W, Wp);
    hipLaunchKernelGGL(mfma_logits_kernel, dim3(MROWS / 128), dim3(256), 0, stream,
                       enc, Wp, bias, proj, attnS);
    hipLaunchKernelGGL(r23_softmax,        dim3(NB),          dim3(256), 0, stream,
                       attnS, out_attn);
    hipLaunchKernelGGL(r23_wsum,           dim3(16 * NB),     dim3(256), 0, stream,
                       enc, out_attn, partials);
    hipLaunchKernelGGL(r23_reduce,         dim3(NB),          dim3(256), 0, stream,
                       partials, out_vec);
}